// Round 3
// baseline (3145.713 us; speedup 1.0000x reference)
//
#include <hip/hip_runtime.h>
#include <math.h>

typedef _Float16 h16;
struct __align__(8) h4v { h16 x, y, z, w; };

struct Stats {
    double sum_d, ss_d, sum_dp, ss_dp;   // global std accumulators
    float inv_d, inv_dp;
    float pad0, pad1;
    float s[5][96];                      // per-channel sums:  0:y1 1:h1 2:g1 3:h2 4:g2
    float q[5][96];                      // per-channel sum-squares
};

struct Params {
    const float *pos, *x; const int *ei;
    const float *aw, *ab;
    const float *linW, *linb, *ling, *linbe;
    const float *rW1, *rb1, *rg1, *rbe1;
    const float *rW2, *rb2, *rgo, *rbo;
    const float *t1, *t2;
    h16 *A, *B;                          // [E,96] fp16 activation + residual stream
    float *dp;
    Stats *st;
    int *cnt, *indptr, *cursor, *elist;
    float *out;
    int E, N;
};

__global__ void zero_k(int* a, int na, int* b, int nb) {
    int gid = blockIdx.x * blockDim.x + threadIdx.x;
    if (gid < na) a[gid] = 0;
    else if (gid - na < nb) b[gid - na] = 0;
}

// Global std (ddof=1) of d=[x_j-x_i | pos_j-pos_i] (99ch) and dp (3ch); stores dp rows.
__global__ __launch_bounds__(256) void s0_k(Params p) {
    int e = blockIdx.x * blockDim.x + threadIdx.x;
    float s = 0.f, ss = 0.f, sp = 0.f, ssp = 0.f;
    if (e < p.E) {
        int i = p.ei[e], j = p.ei[p.E + e];
        const float4* xi = (const float4*)(p.x + (size_t)i * 96);
        const float4* xj = (const float4*)(p.x + (size_t)j * 96);
#pragma unroll
        for (int u = 0; u < 24; u++) {
            float4 a = xi[u], b = xj[u];
            float d0 = b.x - a.x, d1 = b.y - a.y, d2 = b.z - a.z, d3 = b.w - a.w;
            s += d0 + d1 + d2 + d3;
            ss += d0 * d0 + d1 * d1 + d2 * d2 + d3 * d3;
        }
#pragma unroll
        for (int r = 0; r < 3; r++) {
            float dv = p.pos[(size_t)j * 3 + r] - p.pos[(size_t)i * 3 + r];
            s += dv; ss += dv * dv; sp += dv; ssp += dv * dv;
            p.dp[(size_t)e * 3 + r] = dv;
        }
    }
#pragma unroll
    for (int o = 32; o > 0; o >>= 1) {
        s += __shfl_down(s, o); ss += __shfl_down(ss, o);
        sp += __shfl_down(sp, o); ssp += __shfl_down(ssp, o);
    }
    __shared__ float red[4][4];
    int w = threadIdx.x >> 6, l = threadIdx.x & 63;
    if (l == 0) { red[w][0] = s; red[w][1] = ss; red[w][2] = sp; red[w][3] = ssp; }
    __syncthreads();
    if (threadIdx.x == 0) {
        double S = 0, SS = 0, SP = 0, SSP = 0;
        for (int u = 0; u < 4; u++) { S += red[u][0]; SS += red[u][1]; SP += red[u][2]; SSP += red[u][3]; }
        atomicAdd(&p.st->sum_d, S); atomicAdd(&p.st->ss_d, SS);
        atomicAdd(&p.st->sum_dp, SP); atomicAdd(&p.st->ss_dp, SSP);
    }
}

__global__ void s0fin_k(Params p) {
    if (threadIdx.x == 0 && blockIdx.x == 0) {
        double n1 = (double)p.E * 99.0;
        double v1 = (p.st->ss_d - p.st->sum_d * p.st->sum_d / n1) / (n1 - 1.0);
        p.st->inv_d = (float)(1.0 / (sqrt(v1) + 1e-5));
        double n2 = (double)p.E * 3.0;
        double v2 = (p.st->ss_dp - p.st->sum_dp * p.st->sum_dp / n2) / (n2 - 1.0);
        p.st->inv_dp = (float)(1.0 / (sqrt(v2) + 1e-5));
    }
}

__global__ void hist_k(Params p) {
    int e = blockIdx.x * blockDim.x + threadIdx.x;
    if (e < p.E) atomicAdd(&p.cnt[p.ei[e]], 1);
}

// single-block chunked Hillis-Steele scan: indptr (exclusive via +1) and cursor
__global__ void scan_k(Params p) {
    __shared__ int sm[1024];
    int t = threadIdx.x;
    int off = 0;
    int nch = (p.N + 1023) / 1024;
    for (int ch = 0; ch < nch; ch++) {
        int idx = ch * 1024 + t;
        int v = (idx < p.N) ? p.cnt[idx] : 0;
        sm[t] = v; __syncthreads();
        for (int d = 1; d < 1024; d <<= 1) {
            int a = (t >= d) ? sm[t - d] : 0;
            __syncthreads();
            sm[t] += a;
            __syncthreads();
        }
        int incl = sm[t];
        int tot = sm[1023];
        if (idx < p.N) {
            p.indptr[idx + 1] = off + incl;
            p.cursor[idx] = off + incl - v;
        }
        if (ch == 0 && t == 0) p.indptr[0] = 0;
        off += tot;
        __syncthreads();
    }
}

__global__ void scat_k(Params p) {
    int e = blockIdx.x * blockDim.x + threadIdx.x;
    if (e < p.E) {
        int n = p.ei[e];
        int pos0 = atomicAdd(&p.cursor[n], 1);
        if ((unsigned)pos0 < (unsigned)p.E) p.elist[pos0] = e;   // defensive
    }
}

// Fused stage + 64-edge-tile GEMM + bias + BN-stats. All GEMM outputs go in-place to A.
// MODE 1: gather/concat/x_rel -> linW(198x96) -> A=y1, stats0
// MODE 2: bn0+relu(A=y1) -> pe mix -> B=xw1; GEMM rW1[0] -> A=h1, stats1
// MODE 3: bn1+relu(A=h1) -> GEMM rW2[0] -> A=g1, stats2
// MODE 4: relu(bnO0(A=g1)+B=xw1) -> B=xw2; GEMM rW1[1] -> A=h2, stats3
// MODE 5: bn1'+relu(A=h2) -> GEMM rW2[1] -> A=g2, stats4
template<int MODE>
__global__ __launch_bounds__(256) void gemm_k(Params p) {
    constexpr int KD = (MODE == 1) ? 198 : 96;
    constexpr int XSZ = KD * 64;
    __shared__ float lds[(MODE == 1) ? 16144 : 9616];
    float* Xs = lds;                    // [KD][64] transposed
    float* Ws = lds + XSZ;              // [32][96] chunk
    float* bnS = lds + XSZ + 3072;
    float* bnB = bnS + 96;
    float* dpl = bnB + 96;              // 64 edges x 3 (MODE 2)
    float* invf = dpl + 192;            // 16 inv-frequencies (MODE 2)
    int tid = threadIdx.x;
    int eb = blockIdx.x * 64;

    if constexpr (MODE >= 2) {
        if (tid < 96) {
            constexpr int si = MODE - 2;
            const float *g, *b;
            if constexpr (MODE == 2) { g = p.ling; b = p.linbe; }
            else if constexpr (MODE == 3) { g = p.rg1; b = p.rbe1; }
            else if constexpr (MODE == 4) { g = p.rgo; b = p.rbo; }
            else { g = p.rg1 + 96; b = p.rbe1 + 96; }
            float m = p.st->s[si][tid] / (float)p.E;
            float v = p.st->q[si][tid] / (float)p.E - m * m;
            float sc = g[tid] * rsqrtf(v + 1e-5f);
            bnS[tid] = sc; bnB[tid] = b[tid] - m * sc;
        }
    }
    if constexpr (MODE == 2) {
        if (tid < 192) {
            float val = 0.f;
            if (eb + tid / 3 < p.E) val = p.dp[(size_t)eb * 3 + tid] * p.st->inv_dp;
            dpl[tid] = val;
        }
        if (tid < 16) invf[tid] = exp2f(-0.41524101186f * (float)tid); // 100^(-k/16)
    }
    __syncthreads();

    if constexpr (MODE == 1) {
        int el = tid >> 2, qq = tid & 3;
        int e = eb + el; bool ve = e < p.E; int ec = ve ? e : 0;
        int i = p.ei[ec], j = p.ei[p.E + ec];
        float invd = p.st->inv_d;
        const float4* xi4 = (const float4*)(p.x + (size_t)i * 96);
        const float4* xj4 = (const float4*)(p.x + (size_t)j * 96);
#pragma unroll
        for (int u = 0; u < 6; u++) {
            int cc = qq * 24 + u * 4;
            float4 a = xi4[cc >> 2], b = xj4[cc >> 2];
            float av[4] = {a.x, a.y, a.z, a.w}, bv[4] = {b.x, b.y, b.z, b.w};
#pragma unroll
            for (int t = 0; t < 4; t++) {
                int c = cc + t;
                Xs[c * 64 + el] = ve ? av[t] : 0.f;
                float rel = p.aw[c] * ((bv[t] - av[t]) * invd) + p.ab[c];
                Xs[(99 + c) * 64 + el] = ve ? rel : 0.f;
            }
        }
        if (qq == 0) {
#pragma unroll
            for (int r = 0; r < 3; r++) {
                float pi = p.pos[(size_t)i * 3 + r], pj = p.pos[(size_t)j * 3 + r];
                Xs[(96 + r) * 64 + el] = ve ? pi : 0.f;
                float rel = p.aw[96 + r] * ((pj - pi) * invd) + p.ab[96 + r];
                Xs[(195 + r) * 64 + el] = ve ? rel : 0.f;
            }
        }
    } else {
#pragma unroll
        for (int r = 0; r < 6; r++) {
            int v4 = r * 256 + tid; int f = v4 * 4; int el = f / 96; int c = f % 96;
            int e = eb + el; bool ve = e < p.E; size_t ec = ve ? (size_t)e : 0;
            size_t gf = ec * 96 + c;
            float vals[4];
            if constexpr (MODE == 2) {
                h4v y = *(const h4v*)(p.A + gf);
                float yv[4] = {(float)y.x, (float)y.y, (float)y.z, (float)y.w};
#pragma unroll
                for (int t = 0; t < 4; t++) {
                    int ch = c + t;
                    float xw0 = fmaxf(0.f, bnS[ch] * yv[t] + bnB[ch]);
                    int qd = ch >> 5, k = (ch & 31) >> 1;
                    float arg = dpl[el * 3 + qd] * invf[k];
                    float pe = (ch & 1) ? __cosf(arg) : __sinf(arg);
                    vals[t] = pe * (xw0 + pe);
                }
            } else if constexpr (MODE == 3 || MODE == 5) {
                h4v h = *(const h4v*)(p.A + gf);
                float hv[4] = {(float)h.x, (float)h.y, (float)h.z, (float)h.w};
#pragma unroll
                for (int t = 0; t < 4; t++) { int ch = c + t; vals[t] = fmaxf(0.f, bnS[ch] * hv[t] + bnB[ch]); }
            } else { // MODE 4
                h4v g = *(const h4v*)(p.A + gf);
                h4v xw = *(const h4v*)(p.B + gf);
                float gv[4] = {(float)g.x, (float)g.y, (float)g.z, (float)g.w};
                float xv[4] = {(float)xw.x, (float)xw.y, (float)xw.z, (float)xw.w};
#pragma unroll
                for (int t = 0; t < 4; t++) { int ch = c + t; vals[t] = fmaxf(0.f, bnS[ch] * gv[t] + bnB[ch] + xv[t]); }
            }
#pragma unroll
            for (int t = 0; t < 4; t++) Xs[(c + t) * 64 + el] = ve ? vals[t] : 0.f;
            if constexpr (MODE == 2 || MODE == 4) {
                if (ve) { h4v o = {(h16)vals[0], (h16)vals[1], (h16)vals[2], (h16)vals[3]}; *(h4v*)(p.B + gf) = o; }
            }
        }
    }

    const float* W; const float* bias;
    if constexpr (MODE == 1) { W = p.linW; bias = p.linb; }
    else if constexpr (MODE == 2) { W = p.rW1; bias = p.rb1; }
    else if constexpr (MODE == 3) { W = p.rW2; bias = p.rb2; }
    else if constexpr (MODE == 4) { W = p.rW1 + 96 * 96; bias = p.rb1 + 96; }
    else { W = p.rW2 + 96 * 96; bias = p.rb2 + 96; }

    float acc[4][6] = {};
    int cg = tid & 15, eg = tid >> 4, e0 = eg * 4;

#define GEMM_STEP(KK) { \
        float4 xq = *(const float4*)&Xs[(kc + (KK)) * 64 + e0]; \
        float xq0 = xq.x, xq1 = xq.y, xq2 = xq.z, xq3 = xq.w; \
        float wv[6]; \
        _Pragma("unroll") \
        for (int jj = 0; jj < 6; jj++) wv[jj] = Ws[(KK) * 96 + cg + 16 * jj]; \
        _Pragma("unroll") \
        for (int jj = 0; jj < 6; jj++) { \
            acc[0][jj] += xq0 * wv[jj]; acc[1][jj] += xq1 * wv[jj]; \
            acc[2][jj] += xq2 * wv[jj]; acc[3][jj] += xq3 * wv[jj]; } }

    for (int kc = 0; kc < KD; kc += 32) {
        int kch = (KD - kc) < 32 ? (KD - kc) : 32;
        __syncthreads();
        for (int u = tid; u < kch * 24; u += 256)
            ((float4*)Ws)[u] = ((const float4*)(W + (size_t)kc * 96))[u];
        __syncthreads();
        if (kch == 32) {
#pragma unroll
            for (int kk = 0; kk < 32; kk++) GEMM_STEP(kk)
        } else {
            for (int kk = 0; kk < kch; kk++) GEMM_STEP(kk)
        }
    }
#undef GEMM_STEP

    float bj[6];
#pragma unroll
    for (int jj = 0; jj < 6; jj++) bj[jj] = bias[cg + 16 * jj];
#pragma unroll
    for (int ii = 0; ii < 4; ii++)
#pragma unroll
        for (int jj = 0; jj < 6; jj++) acc[ii][jj] += bj[jj];

#pragma unroll
    for (int ii = 0; ii < 4; ii++) {
        int e = eb + e0 + ii;
        if (e < p.E) {
#pragma unroll
            for (int jj = 0; jj < 6; jj++)
                p.A[(size_t)e * 96 + cg + 16 * jj] = (h16)acc[ii][jj];
        }
    }

    // per-channel stats reduction (reuse Xs region; f32 pre-rounding accumulators)
    __syncthreads();
    float* rs = lds; float* rq = lds + 96 * 17;
#pragma unroll
    for (int jj = 0; jj < 6; jj++) {
        float s = 0.f, q2 = 0.f;
#pragma unroll
        for (int ii = 0; ii < 4; ii++) {
            if (eb + e0 + ii < p.E) { float a = acc[ii][jj]; s += a; q2 += a * a; }
        }
        rs[(cg + 16 * jj) * 17 + eg] = s;
        rq[(cg + 16 * jj) * 17 + eg] = q2;
    }
    __syncthreads();
    if (tid < 96) {
        float s = 0.f, q2 = 0.f;
        for (int g2 = 0; g2 < 16; g2++) { s += rs[tid * 17 + g2]; q2 += rq[tid * 17 + g2]; }
        constexpr int so = MODE - 1;
        atomicAdd(&p.st->s[so][tid], s);
        atomicAdd(&p.st->q[so][tid], q2);
    }
}

// out_x = relu(bnO1(g2) + xw2)  (A <- f(A,B)), fp16 in/out
__global__ __launch_bounds__(256) void k6_k(Params p) {
    __shared__ float bnS[96], bnB[96];
    if (threadIdx.x < 96) {
        float m = p.st->s[4][threadIdx.x] / (float)p.E;
        float v = p.st->q[4][threadIdx.x] / (float)p.E - m * m;
        float sc = p.rgo[96 + threadIdx.x] * rsqrtf(v + 1e-5f);
        bnS[threadIdx.x] = sc; bnB[threadIdx.x] = p.rbo[96 + threadIdx.x] - m * sc;
    }
    __syncthreads();
    size_t total = (size_t)p.E * 24;
    for (size_t v4 = (size_t)blockIdx.x * blockDim.x + threadIdx.x; v4 < total;
         v4 += (size_t)gridDim.x * blockDim.x) {
        int c = (int)((v4 * 4) % 96);
        h4v g = ((const h4v*)p.A)[v4];
        h4v xw = ((const h4v*)p.B)[v4];
        h4v r;
        r.x = (h16)fmaxf(0.f, bnS[c] * (float)g.x + bnB[c] + (float)xw.x);
        r.y = (h16)fmaxf(0.f, bnS[c + 1] * (float)g.y + bnB[c + 1] + (float)xw.y);
        r.z = (h16)fmaxf(0.f, bnS[c + 2] * (float)g.z + bnB[c + 2] + (float)xw.z);
        r.w = (h16)fmaxf(0.f, bnS[c + 3] * (float)g.w + bnB[c + 3] + (float)xw.w);
        ((h4v*)p.A)[v4] = r;
    }
}

// dual-temperature segment softmax aggregation, one thread per (node, channel)
__global__ __launch_bounds__(256) void agg_k(Params p) {
    int gid = blockIdx.x * blockDim.x + threadIdx.x;
    if (gid >= p.N * 96) return;
    int n = gid / 96, c = gid % 96;
    int s0 = p.indptr[n], s1 = p.indptr[n + 1];
    s0 = s0 < 0 ? 0 : (s0 > p.E ? p.E : s0);               // defensive clamps
    s1 = s1 < s0 ? s0 : (s1 > p.E ? p.E : s1);
    float t1 = p.t1[c], t2 = p.t2[c];
    float m1 = -INFINITY, m2 = -INFINITY;
    for (int u = s0; u < s1; u++) {
        unsigned e = (unsigned)p.elist[u];
        if (e >= (unsigned)p.E) continue;
        float v = (float)p.A[(size_t)e * 96 + c];
        m1 = fmaxf(m1, v * t1); m2 = fmaxf(m2, v * t2);
    }
    float se1 = 0.f, sv1 = 0.f, se2 = 0.f, sv2 = 0.f;
    for (int u = s0; u < s1; u++) {
        unsigned e = (unsigned)p.elist[u];
        if (e >= (unsigned)p.E) continue;
        float v = (float)p.A[(size_t)e * 96 + c];
        float e1 = __expf(v * t1 - m1); se1 += e1; sv1 += v * e1;
        float e2 = __expf(v * t2 - m2); se2 += e2; sv2 += v * e2;
    }
    p.out[gid] = sv1 / (se1 + 1e-16f) + sv2 / (se2 + 1e-16f);
}

extern "C" void kernel_launch(void* const* d_in, const int* in_sizes, int n_in,
                              void* d_out, int out_size, void* d_ws, size_t ws_size,
                              hipStream_t stream) {
    Params p;
    p.pos = (const float*)d_in[0]; p.x = (const float*)d_in[1]; p.ei = (const int*)d_in[2];
    p.aw = (const float*)d_in[3]; p.ab = (const float*)d_in[4];
    p.linW = (const float*)d_in[5]; p.linb = (const float*)d_in[6];
    p.ling = (const float*)d_in[7]; p.linbe = (const float*)d_in[8];
    p.rW1 = (const float*)d_in[9]; p.rb1 = (const float*)d_in[10];
    p.rg1 = (const float*)d_in[11]; p.rbe1 = (const float*)d_in[12];
    p.rW2 = (const float*)d_in[13]; p.rb2 = (const float*)d_in[14];
    p.rgo = (const float*)d_in[15]; p.rbo = (const float*)d_in[16];
    p.t1 = (const float*)d_in[17]; p.t2 = (const float*)d_in[18];
    int E = in_sizes[2] / 2, N = in_sizes[0] / 3;
    p.E = E; p.N = N;

    char* w0 = (char*)d_ws;
    char* w = w0;
    auto alloc = [&](size_t bytes) { char* r = w; w += (bytes + 15) & ~15ull; return r; };
    size_t EH = (size_t)E * 96 * sizeof(h16);              // 115.2 MB
    p.A = (h16*)alloc(EH);
    p.B = (h16*)alloc(EH);
    p.dp = (float*)alloc((size_t)E * 3 * sizeof(float));
    p.st = (Stats*)alloc(sizeof(Stats));
    p.cnt = (int*)alloc((size_t)N * 4);
    p.indptr = (int*)alloc((size_t)(N + 1) * 4);
    p.cursor = (int*)alloc((size_t)N * 4);
    p.elist = (int*)alloc((size_t)E * 4);
    p.out = (float*)d_out;

    size_t need = (size_t)(w - w0);
    if (need > ws_size) {
        // Workspace too small: fail soft with a clean absmax (diagnostic), not a fault.
        hipMemsetAsync(d_out, 0, (size_t)out_size * sizeof(float), stream);
        return;
    }

    int nz = (int)(sizeof(Stats) / 4);
    zero_k<<<(nz + N + 255) / 256, 256, 0, stream>>>((int*)p.st, nz, p.cnt, N);
    s0_k<<<(E + 255) / 256, 256, 0, stream>>>(p);
    s0fin_k<<<1, 64, 0, stream>>>(p);
    hist_k<<<(E + 255) / 256, 256, 0, stream>>>(p);
    scan_k<<<1, 1024, 0, stream>>>(p);
    scat_k<<<(E + 255) / 256, 256, 0, stream>>>(p);
    int gE = (E + 63) / 64;
    gemm_k<1><<<gE, 256, 0, stream>>>(p);
    gemm_k<2><<<gE, 256, 0, stream>>>(p);
    gemm_k<3><<<gE, 256, 0, stream>>>(p);
    gemm_k<4><<<gE, 256, 0, stream>>>(p);
    gemm_k<5><<<gE, 256, 0, stream>>>(p);
    k6_k<<<2048, 256, 0, stream>>>(p);
    agg_k<<<(N * 96 + 255) / 256, 256, 0, stream>>>(p);
}

// Round 5
// 1430.568 us; speedup vs baseline: 2.1989x; 2.1989x over previous
//
#include <hip/hip_runtime.h>
#include <math.h>

typedef _Float16 h16;
typedef _Float16 f16x8 __attribute__((ext_vector_type(8)));
typedef _Float16 f16x4 __attribute__((ext_vector_type(4)));
typedef float f32x4 __attribute__((ext_vector_type(4)));

struct Stats {
    double sum_d, ss_d, sum_dp, ss_dp;
    float inv_d, inv_dp, pad0, pad1;
    float s[5][96];   // 0:y1 1:h1 2:g1pre 3:h2 4:g2pre
    float q[5][96];
};

struct Params {
    const float *pos, *x; const int *ei;
    const float *aw, *ab;
    const float *linW, *linb, *ling, *linbe;
    const float *rW1, *rb1, *rg1, *rbe1;
    const float *rW2, *rb2, *rgo, *rbo;
    const float *t1, *t2;
    h16 *A, *B;            // [E,96] activation + residual stream (fp16)
    h16 *P;                // [N,192] node-level products (aliases d_out)
    h16 *Wt4;              // [4][96][96] transposed res weights fp16
    h16 *Wt192;            // [192][128] combined lin weights fp16
    h16 *c0;               // [96]
    Stats *st;
    int *cnt, *indptr, *cursor, *elist;
    float *out;
    int E, N;
};

__global__ void zero_k(int* a, int na, int* b, int nb) {
    int gid = blockIdx.x * blockDim.x + threadIdx.x;
    if (gid < na) a[gid] = 0;
    else if (gid - na < nb) b[gid - na] = 0;
}

// Global std (ddof=1) of d=[x_j-x_i | pos_j-pos_i] (99ch) and dp (3ch).
__global__ __launch_bounds__(256) void s0_k(Params p) {
    int e = blockIdx.x * blockDim.x + threadIdx.x;
    float s = 0.f, ss = 0.f, sp = 0.f, ssp = 0.f;
    if (e < p.E) {
        int i = p.ei[e], j = p.ei[p.E + e];
        const float4* xi = (const float4*)(p.x + (size_t)i * 96);
        const float4* xj = (const float4*)(p.x + (size_t)j * 96);
#pragma unroll
        for (int u = 0; u < 24; u++) {
            float4 a = xi[u], b = xj[u];
            float d0 = b.x - a.x, d1 = b.y - a.y, d2 = b.z - a.z, d3 = b.w - a.w;
            s += d0 + d1 + d2 + d3;
            ss += d0 * d0 + d1 * d1 + d2 * d2 + d3 * d3;
        }
#pragma unroll
        for (int r = 0; r < 3; r++) {
            float dv = p.pos[(size_t)j * 3 + r] - p.pos[(size_t)i * 3 + r];
            s += dv; ss += dv * dv; sp += dv; ssp += dv * dv;
        }
    }
#pragma unroll
    for (int o = 32; o > 0; o >>= 1) {
        s += __shfl_down(s, o); ss += __shfl_down(ss, o);
        sp += __shfl_down(sp, o); ssp += __shfl_down(ssp, o);
    }
    __shared__ float red[4][4];
    int w = threadIdx.x >> 6, l = threadIdx.x & 63;
    if (l == 0) { red[w][0] = s; red[w][1] = ss; red[w][2] = sp; red[w][3] = ssp; }
    __syncthreads();
    if (threadIdx.x == 0) {
        double S = 0, SS = 0, SP = 0, SSP = 0;
        for (int u = 0; u < 4; u++) { S += red[u][0]; SS += red[u][1]; SP += red[u][2]; SSP += red[u][3]; }
        atomicAdd(&p.st->sum_d, S); atomicAdd(&p.st->ss_d, SS);
        atomicAdd(&p.st->sum_dp, SP); atomicAdd(&p.st->ss_dp, SSP);
    }
}

__global__ void s0fin_k(Params p) {
    if (threadIdx.x == 0 && blockIdx.x == 0) {
        double n1 = (double)p.E * 99.0;
        double v1 = (p.st->ss_d - p.st->sum_d * p.st->sum_d / n1) / (n1 - 1.0);
        p.st->inv_d = (float)(1.0 / (sqrt(v1) + 1e-5));
        double n2 = (double)p.E * 3.0;
        double v2 = (p.st->ss_dp - p.st->sum_dp * p.st->sum_dp / n2) / (n2 - 1.0);
        p.st->inv_dp = (float)(1.0 / (sqrt(v2) + 1e-5));
    }
}

// Transpose res weights to [ch][k] fp16: idx 0=rW1[0],1=rW2[0],2=rW1[1],3=rW2[1]
__global__ void wtrans_k(Params p) {
    int gid = blockIdx.x * 256 + threadIdx.x;
    if (gid >= 4 * 9216) return;
    int m = gid / 9216, r = gid % 9216, ch = r / 96, k = r % 96;
    const float* W = (m == 0) ? p.rW1 : (m == 1) ? p.rW2 : (m == 2) ? p.rW1 + 9216 : p.rW2 + 9216;
    p.Wt4[gid] = (h16)W[k * 96 + ch];
}

// Combined lin weights: Wt192[ch][kk]; ch<96: (Wt - inv_d*diag(aw)*Wb)^T, ch>=96: (inv_d*diag(aw)*Wb)^T; K padded to 128.
__global__ void wprep_k(Params p) {
    int gid = blockIdx.x * 256 + threadIdx.x;
    if (gid >= 192 * 128) return;
    int ch = gid / 128, kk = gid % 128;
    float v = 0.f;
    if (kk < 99) {
        float invd = p.st->inv_d;
        float wb = p.aw[kk] * invd;
        if (ch < 96) v = p.linW[kk * 96 + ch] - wb * p.linW[(99 + kk) * 96 + ch];
        else         v = wb * p.linW[(99 + kk) * 96 + (ch - 96)];
    }
    p.Wt192[gid] = (h16)v;
}

__global__ void c0_k(Params p) {
    int c = threadIdx.x;
    if (c >= 96) return;
    float s = p.linb[c];
    for (int k = 0; k < 99; k++) s += p.ab[k] * p.linW[(99 + k) * 96 + c];
    p.c0[c] = (h16)s;
}

__global__ void hist_k(Params p) {
    int e = blockIdx.x * blockDim.x + threadIdx.x;
    if (e < p.E) atomicAdd(&p.cnt[p.ei[e]], 1);
}

__global__ void scan_k(Params p) {
    __shared__ int sm[1024];
    int t = threadIdx.x;
    int off = 0;
    int nch = (p.N + 1023) / 1024;
    for (int ch = 0; ch < nch; ch++) {
        int idx = ch * 1024 + t;
        int v = (idx < p.N) ? p.cnt[idx] : 0;
        sm[t] = v; __syncthreads();
        for (int d = 1; d < 1024; d <<= 1) {
            int a = (t >= d) ? sm[t - d] : 0;
            __syncthreads();
            sm[t] += a;
            __syncthreads();
        }
        int incl = sm[t];
        int tot = sm[1023];
        if (idx < p.N) {
            p.indptr[idx + 1] = off + incl;
            p.cursor[idx] = off + incl - v;
        }
        if (ch == 0 && t == 0) p.indptr[0] = 0;
        off += tot;
        __syncthreads();
    }
}

__global__ void scat_k(Params p) {
    int e = blockIdx.x * blockDim.x + threadIdx.x;
    if (e < p.E) {
        int n = p.ei[e];
        int pos0 = atomicAdd(&p.cursor[n], 1);
        if ((unsigned)pos0 < (unsigned)p.E) p.elist[pos0] = e;
    }
}

// Node-level GEMM: P[node,0:192] = xcat[node,0:128pad] . Wt192^T  (fp16 MFMA, f32 acc)
__global__ __launch_bounds__(256) void pgemm_k(Params p) {
    __shared__ __align__(16) char lds[81920];   // X 128x256B | W 192x256B, XOR-swizzled
    int tid = threadIdx.x;
    int nb = blockIdx.x * 128;
    // stage X (x features)
    for (int u = tid; u < 3072; u += 256) {
        int node = u / 24, c4 = (u % 24) * 4;
        int gn = nb + node;
        float4 xv = make_float4(0.f, 0.f, 0.f, 0.f);
        if (gn < p.N) xv = *(const float4*)(p.x + (size_t)gn * 96 + c4);
        f16x4 hv = { (h16)xv.x, (h16)xv.y, (h16)xv.z, (h16)xv.w };
        int su = (c4 >> 3) ^ (node & 7);
        *(f16x4*)(lds + node * 256 + su * 16 + ((c4 & 7) * 2)) = hv;
    }
    // pos rows 96..98 + zero pad 99..127
    if (tid < 128) {
        int node = tid, gn = nb + node;
        f16x8 pv = {};
        if (gn < p.N) { pv[0] = (h16)p.pos[gn * 3]; pv[1] = (h16)p.pos[gn * 3 + 1]; pv[2] = (h16)p.pos[gn * 3 + 2]; }
        f16x8 z = {};
        *(f16x8*)(lds + node * 256 + (12 ^ (node & 7)) * 16) = pv;
        *(f16x8*)(lds + node * 256 + (13 ^ (node & 7)) * 16) = z;
        *(f16x8*)(lds + node * 256 + (14 ^ (node & 7)) * 16) = z;
        *(f16x8*)(lds + node * 256 + (15 ^ (node & 7)) * 16) = z;
    }
    // stage W
    for (int u = tid; u < 3072; u += 256) {
        int ch = u >> 4, un = u & 15;
        f16x8 wv = *(const f16x8*)(p.Wt192 + ch * 128 + un * 8);
        *(f16x8*)(lds + 32768 + ch * 256 + (un ^ (ch & 7)) * 16) = wv;
    }
    __syncthreads();
    int lane = tid & 63, w = tid >> 6, lr = lane & 15, lg = lane >> 4;
    f32x4 acc[2][12] = {};
    for (int kc = 0; kc < 4; kc++) {
        int ub = kc * 4 + lg;
        int r0 = w * 32 + lr, r1 = r0 + 16;
        f16x8 a0 = *(f16x8*)(lds + r0 * 256 + (ub ^ (r0 & 7)) * 16);
        f16x8 a1 = *(f16x8*)(lds + r1 * 256 + (ub ^ (r1 & 7)) * 16);
#pragma unroll
        for (int ni = 0; ni < 12; ni++) {
            int ch = ni * 16 + lr;
            f16x8 b = *(f16x8*)(lds + 32768 + ch * 256 + (ub ^ (ch & 7)) * 16);
            acc[0][ni] = __builtin_amdgcn_mfma_f32_16x16x32_f16(a0, b, acc[0][ni], 0, 0, 0);
            acc[1][ni] = __builtin_amdgcn_mfma_f32_16x16x32_f16(a1, b, acc[1][ni], 0, 0, 0);
        }
    }
#pragma unroll
    for (int mi = 0; mi < 2; mi++)
#pragma unroll
        for (int ni = 0; ni < 12; ni++)
#pragma unroll
            for (int r = 0; r < 4; r++) {
                int node = nb + w * 32 + mi * 16 + lg * 4 + r;
                if (node < p.N) p.P[(size_t)node * 192 + ni * 16 + lr] = (h16)acc[mi][ni][r];
            }
}

// y1[e] = P[i,0:96] + P[j,96:192] + c0  -> A (fp16) + stats0
__global__ __launch_bounds__(192) void asm_k(Params p) {
    __shared__ float ls[96], lq[96];
    __shared__ __align__(16) h16 c0s[96];
    int tid = threadIdx.x;
    if (tid < 96) { ls[tid] = 0.f; lq[tid] = 0.f; c0s[tid] = p.c0[tid]; }
    __syncthreads();
    int u = tid % 12;
    float s[8] = {}, q[8] = {};
    size_t total = (size_t)p.E * 12;
    for (size_t f = (size_t)blockIdx.x * 192 + tid; f < total; f += (size_t)gridDim.x * 192) {
        int e = (int)(f / 12);
        int i = p.ei[e], j = p.ei[p.E + e];
        f16x8 a = *(const f16x8*)(p.P + (size_t)i * 192 + u * 8);
        f16x8 b = *(const f16x8*)(p.P + (size_t)j * 192 + 96 + u * 8);
        f16x8 c = *(const f16x8*)(c0s + u * 8);
        f16x8 o;
#pragma unroll
        for (int t = 0; t < 8; t++) {
            float v = (float)a[t] + (float)b[t] + (float)c[t];
            o[t] = (h16)v; s[t] += v; q[t] += v * v;
        }
        *(f16x8*)(p.A + (size_t)e * 96 + u * 8) = o;
    }
#pragma unroll
    for (int t = 0; t < 8; t++) { atomicAdd(&ls[u * 8 + t], s[t]); atomicAdd(&lq[u * 8 + t], q[t]); }
    __syncthreads();
    if (tid < 96) { atomicAdd(&p.st->s[0][tid], ls[tid]); atomicAdd(&p.st->q[0][tid], lq[tid]); }
}

// Fused elementwise + 128-edge fp16 MFMA GEMM + bias + stats.
// M=2: xw1=pe*(relu(bn0(A))+pe) -> B; GEMM W1[0] -> A=h1, stats1
// M=3: relu(bn1(A)) -> GEMM W2[0] -> A=g1pre, stats2
// M=4: xw2=relu(bnO0(A)+B) -> B; GEMM W1[1] -> A=h2, stats3
// M=5: relu(bn1'(A)) -> GEMM W2[1] -> A=g2pre, stats4
template<int M>
__global__ __launch_bounds__(256) void edge_k(Params p) {
    __shared__ __align__(16) char lds[45760];
    // 0..24576 X[128][192B rot-swz] ; 24576..43008 W[96][192B rot-swz]
    // 43008 bnS | 43392 bnB | 43776 bias | 44160 dpl(1536B) | 45696 invf
    // post-GEMM reuse: 0..26624 out[128][208B] ; 27648 sredS ; 33792 sredQ
    float* bnS = (float*)(lds + 43008);
    float* bnB = (float*)(lds + 43392);
    float* biasL = (float*)(lds + 43776);
    float* dpl = (float*)(lds + 44160);
    float* invf = (float*)(lds + 45696);
    int tid = threadIdx.x;
    int eb = blockIdx.x * 128;
    constexpr int SI = M - 2;
    if (tid < 96) {
        const float *g, *b;
        if constexpr (M == 2) { g = p.ling; b = p.linbe; }
        else if constexpr (M == 3) { g = p.rg1; b = p.rbe1; }
        else if constexpr (M == 4) { g = p.rgo; b = p.rbo; }
        else { g = p.rg1 + 96; b = p.rbe1 + 96; }
        float m = p.st->s[SI][tid] / (float)p.E;
        float v = p.st->q[SI][tid] / (float)p.E - m * m;
        float sc = g[tid] * rsqrtf(v + 1e-5f);
        bnS[tid] = sc; bnB[tid] = b[tid] - m * sc;
        const float* bias = (M == 2) ? p.rb1 : (M == 3) ? p.rb2 : (M == 4) ? p.rb1 + 96 : p.rb2 + 96;
        biasL[tid] = bias[tid];
    }
    if constexpr (M == 2) {
        // FIX (round 4 bug): 384 entries but only 256 threads -> strided loop,
        // previously `if (tid < 384)` left dpl[256..383] uninitialized.
        for (int u = tid; u < 384; u += 256) {
            int e = eb + u / 3, r = u % 3;
            float v = 0.f;
            if (e < p.E) {
                int i = p.ei[e], j = p.ei[p.E + e];
                v = (p.pos[(size_t)j * 3 + r] - p.pos[(size_t)i * 3 + r]) * p.st->inv_dp;
            }
            dpl[u] = v;
        }
        if (tid < 16) invf[tid] = exp2f(-0.41524101186f * (float)tid);   // 100^(-k/16)
    }
    // stage W (pre-transposed fp16, rotation swizzle)
    const h16* Wg = p.Wt4 + (M - 2) * 9216;
    for (int u = tid; u < 1152; u += 256) {
        int ch = u / 12, un = u % 12;
        f16x8 wv = *(const f16x8*)(Wg + ch * 96 + un * 8);
        *(f16x8*)(lds + 24576 + ch * 192 + ((un + ch) % 12) * 16) = wv;
    }
    __syncthreads();
    // stage X (+ B write for M=2/4)
    for (int u = tid; u < 1536; u += 256) {
        int el = u / 12, c8 = (u % 12) * 8;
        int e = eb + el; bool ve = e < p.E;
        size_t gf = (size_t)(ve ? e : 0) * 96 + c8;
        f16x8 av = {};
        if (ve) av = *(const f16x8*)(p.A + gf);
        f16x8 o;
        if constexpr (M == 2) {
#pragma unroll
            for (int t = 0; t < 8; t++) {
                int ch = c8 + t;
                float xw0 = fmaxf(0.f, bnS[ch] * (float)av[t] + bnB[ch]);
                int qd = ch >> 5, k = (ch & 31) >> 1;
                float arg = dpl[el * 3 + qd] * invf[k];
                float pe = (ch & 1) ? __cosf(arg) : __sinf(arg);
                o[t] = (h16)(pe * (xw0 + pe));
            }
        } else if constexpr (M == 4) {
            f16x8 bv = {};
            if (ve) bv = *(const f16x8*)(p.B + gf);
#pragma unroll
            for (int t = 0; t < 8; t++) {
                int ch = c8 + t;
                o[t] = (h16)fmaxf(0.f, bnS[ch] * (float)av[t] + bnB[ch] + (float)bv[t]);
            }
        } else {
#pragma unroll
            for (int t = 0; t < 8; t++) {
                int ch = c8 + t;
                o[t] = (h16)fmaxf(0.f, bnS[ch] * (float)av[t] + bnB[ch]);
            }
        }
        if constexpr (M == 2 || M == 4) { if (ve) *(f16x8*)(p.B + gf) = o; }
        *(f16x8*)(lds + el * 192 + ((c8 / 8 + el) % 12) * 16) = o;
    }
    __syncthreads();
    // MFMA GEMM: per wave 32 edges x 96 ch, K=96
    int lane = tid & 63, w = tid >> 6, lr = lane & 15, lg = lane >> 4;
    f32x4 acc[2][6] = {};
#pragma unroll
    for (int kc = 0; kc < 3; kc++) {
        int ub = kc * 4 + lg;
        int r0 = w * 32 + lr, r1 = r0 + 16;
        f16x8 a0 = *(f16x8*)(lds + r0 * 192 + ((ub + r0) % 12) * 16);
        f16x8 a1 = *(f16x8*)(lds + r1 * 192 + ((ub + r1) % 12) * 16);
#pragma unroll
        for (int ni = 0; ni < 6; ni++) {
            int ch = ni * 16 + lr;
            f16x8 b = *(f16x8*)(lds + 24576 + ch * 192 + ((ub + ch) % 12) * 16);
            acc[0][ni] = __builtin_amdgcn_mfma_f32_16x16x32_f16(a0, b, acc[0][ni], 0, 0, 0);
            acc[1][ni] = __builtin_amdgcn_mfma_f32_16x16x32_f16(a1, b, acc[1][ni], 0, 0, 0);
        }
    }
    __syncthreads();   // all LDS reads done; reuse for out-stage + stats
    float* sredS = (float*)(lds + 27648);
    float* sredQ = (float*)(lds + 33792);
#pragma unroll
    for (int ni = 0; ni < 6; ni++) {
        int ch = ni * 16 + lr;
        float bj = biasL[ch];
        float s = 0.f, q = 0.f;
#pragma unroll
        for (int mi = 0; mi < 2; mi++)
#pragma unroll
            for (int r = 0; r < 4; r++) {
                float v = acc[mi][ni][r] + bj;
                int el = w * 32 + mi * 16 + lg * 4 + r;
                ((h16*)(lds + el * 208))[ch] = (h16)v;
                if (eb + el < p.E) { s += v; q += v * v; }
            }
        sredS[ch * 16 + w * 4 + lg] = s;
        sredQ[ch * 16 + w * 4 + lg] = q;
    }
    __syncthreads();
    constexpr int SO = M - 1;
    if (tid < 96) {
        float s = 0.f, q = 0.f;
#pragma unroll
        for (int t = 0; t < 16; t++) { s += sredS[tid * 16 + t]; q += sredQ[tid * 16 + t]; }
        atomicAdd(&p.st->s[SO][tid], s);
        atomicAdd(&p.st->q[SO][tid], q);
    }
    // coalesced writeback
    for (int u = tid; u < 1536; u += 256) {
        int el = u / 12, c8u = u % 12;
        int e = eb + el;
        if (e < p.E) {
            f16x8 v = *(f16x8*)(lds + el * 208 + c8u * 16);
            *(f16x8*)(p.A + (size_t)e * 96 + c8u * 8) = v;
        }
    }
}

// out_x = relu(bnO1(A=g2pre) + B=xw2) -> A (fp16)
__global__ __launch_bounds__(256) void k6_k(Params p) {
    __shared__ float bnS[96], bnB[96];
    if (threadIdx.x < 96) {
        float m = p.st->s[4][threadIdx.x] / (float)p.E;
        float v = p.st->q[4][threadIdx.x] / (float)p.E - m * m;
        float sc = p.rgo[96 + threadIdx.x] * rsqrtf(v + 1e-5f);
        bnS[threadIdx.x] = sc; bnB[threadIdx.x] = p.rbo[96 + threadIdx.x] - m * sc;
    }
    __syncthreads();
    size_t total = (size_t)p.E * 12;
    for (size_t u = (size_t)blockIdx.x * blockDim.x + threadIdx.x; u < total;
         u += (size_t)gridDim.x * blockDim.x) {
        int c = (int)((u * 8) % 96);
        f16x8 g = ((const f16x8*)p.A)[u];
        f16x8 xw = ((const f16x8*)p.B)[u];
        f16x8 r;
#pragma unroll
        for (int t = 0; t < 8; t++)
            r[t] = (h16)fmaxf(0.f, bnS[c + t] * (float)g[t] + bnB[c + t] + (float)xw[t]);
        ((f16x8*)p.A)[u] = r;
    }
}

// dual-temperature segment softmax aggregation
__global__ __launch_bounds__(256) void agg_k(Params p) {
    int gid = blockIdx.x * blockDim.x + threadIdx.x;
    if (gid >= p.N * 96) return;
    int n = gid / 96, c = gid % 96;
    int s0 = p.indptr[n], s1 = p.indptr[n + 1];
    s0 = s0 < 0 ? 0 : (s0 > p.E ? p.E : s0);
    s1 = s1 < s0 ? s0 : (s1 > p.E ? p.E : s1);
    float t1 = p.t1[c], t2 = p.t2[c];
    float m1 = -INFINITY, m2 = -INFINITY;
    for (int u = s0; u < s1; u++) {
        unsigned e = (unsigned)p.elist[u];
        if (e >= (unsigned)p.E) continue;
        float v = (float)p.A[(size_t)e * 96 + c];
        m1 = fmaxf(m1, v * t1); m2 = fmaxf(m2, v * t2);
    }
    float se1 = 0.f, sv1 = 0.f, se2 = 0.f, sv2 = 0.f;
    for (int u = s0; u < s1; u++) {
        unsigned e = (unsigned)p.elist[u];
        if (e >= (unsigned)p.E) continue;
        float v = (float)p.A[(size_t)e * 96 + c];
        float e1 = __expf(v * t1 - m1); se1 += e1; sv1 += v * e1;
        float e2 = __expf(v * t2 - m2); se2 += e2; sv2 += v * e2;
    }
    p.out[gid] = sv1 / (se1 + 1e-16f) + sv2 / (se2 + 1e-16f);
}

extern "C" void kernel_launch(void* const* d_in, const int* in_sizes, int n_in,
                              void* d_out, int out_size, void* d_ws, size_t ws_size,
                              hipStream_t stream) {
    Params p;
    p.pos = (const float*)d_in[0]; p.x = (const float*)d_in[1]; p.ei = (const int*)d_in[2];
    p.aw = (const float*)d_in[3]; p.ab = (const float*)d_in[4];
    p.linW = (const float*)d_in[5]; p.linb = (const float*)d_in[6];
    p.ling = (const float*)d_in[7]; p.linbe = (const float*)d_in[8];
    p.rW1 = (const float*)d_in[9]; p.rb1 = (const float*)d_in[10];
    p.rg1 = (const float*)d_in[11]; p.rbe1 = (const float*)d_in[12];
    p.rW2 = (const float*)d_in[13]; p.rb2 = (const float*)d_in[14];
    p.rgo = (const float*)d_in[15]; p.rbo = (const float*)d_in[16];
    p.t1 = (const float*)d_in[17]; p.t2 = (const float*)d_in[18];
    int E = in_sizes[2] / 2, N = in_sizes[0] / 3;
    p.E = E; p.N = N;

    char* w0 = (char*)d_ws;
    char* w = w0;
    auto alloc = [&](size_t bytes) { char* r = w; w += (bytes + 255) & ~255ull; return r; };
    size_t EH = (size_t)E * 96 * sizeof(h16);
    p.A = (h16*)alloc(EH);
    p.B = (h16*)alloc(EH);
    p.st = (Stats*)alloc(sizeof(Stats));
    p.cnt = (int*)alloc((size_t)N * 4);
    p.indptr = (int*)alloc((size_t)(N + 1) * 4);
    p.cursor = (int*)alloc((size_t)N * 4);
    p.elist = (int*)alloc((size_t)E * 4);
    p.Wt4 = (h16*)alloc(4 * 9216 * sizeof(h16));
    p.Wt192 = (h16*)alloc(192 * 128 * sizeof(h16));
    p.c0 = (h16*)alloc(96 * sizeof(h16));
    p.P = (h16*)d_out;          // [N,192] fp16 == out_size*4 bytes, dead until agg
    p.out = (float*)d_out;

    size_t need = (size_t)(w - w0);
    if (need > ws_size) {
        hipMemsetAsync(d_out, 0, (size_t)out_size * sizeof(float), stream);
        return;
    }

    int nz = (int)(sizeof(Stats) / 4);
    zero_k<<<(nz + N + 255) / 256, 256, 0, stream>>>((int*)p.st, nz, p.cnt, N);
    s0_k<<<(E + 255) / 256, 256, 0, stream>>>(p);
    s0fin_k<<<1, 64, 0, stream>>>(p);
    wtrans_k<<<(4 * 9216 + 255) / 256, 256, 0, stream>>>(p);
    wprep_k<<<(192 * 128 + 255) / 256, 256, 0, stream>>>(p);
    c0_k<<<1, 96, 0, stream>>>(p);
    hist_k<<<(E + 255) / 256, 256, 0, stream>>>(p);
    scan_k<<<1, 1024, 0, stream>>>(p);
    scat_k<<<(E + 255) / 256, 256, 0, stream>>>(p);
    pgemm_k<<<(N + 127) / 128, 256, 0, stream>>>(p);
    asm_k<<<1536, 192, 0, stream>>>(p);
    int gE = (E + 127) / 128;
    edge_k<2><<<gE, 256, 0, stream>>>(p);
    edge_k<3><<<gE, 256, 0, stream>>>(p);
    edge_k<4><<<gE, 256, 0, stream>>>(p);
    edge_k<5><<<gE, 256, 0, stream>>>(p);
    k6_k<<<2048, 256, 0, stream>>>(p);
    agg_k<<<(N * 96 + 255) / 256, 256, 0, stream>>>(p);
}